// Round 5
// baseline (672.789 us; speedup 1.0000x reference)
//
#include <hip/hip_runtime.h>
#include <hip/hip_bf16.h>

#define D 512
#define L_LAYERS 2
#define BATCH 8
#define TT 2048
#define N3 1536   // 3*D
#define REC 4096  // BATCH*D

typedef __attribute__((ext_vector_type(8))) short short8;
typedef __attribute__((ext_vector_type(4))) float floatx4;

#if __has_builtin(__builtin_amdgcn_exp2f)
#define EXP2F(x) __builtin_amdgcn_exp2f(x)
#else
#define EXP2F(x) exp2f(x)
#endif
#if __has_builtin(__builtin_amdgcn_rcpf)
#define RCPF(x) __builtin_amdgcn_rcpf(x)
#else
#define RCPF(x) (1.0f / (x))
#endif

__device__ __forceinline__ unsigned short f2bf(float f) {
  unsigned u = __builtin_bit_cast(unsigned, f);
  u += 0x7FFFu + ((u >> 16) & 1u);
  return (unsigned short)(u >> 16);
}

// ---- embedding gather: xa[(t*B+b)*D + d] = bf16(emb[ids[b][t]][d])
__global__ __launch_bounds__(128) void embed_kernel(const int* __restrict__ ids,
                                                    const float* __restrict__ emb,
                                                    unsigned short* __restrict__ xa) {
  int bt = blockIdx.x;          // b*T + t
  int b = bt >> 11;
  int t = bt & 2047;
  int id = ids[bt];
  int d = threadIdx.x << 2;
  const float4 v = *(const float4*)(emb + (size_t)id * D + d);
  ushort4 w;
  w.x = f2bf(v.x); w.y = f2bf(v.y); w.z = f2bf(v.z); w.w = f2bf(v.w);
  *(ushort4*)(xa + ((size_t)t * BATCH + b) * D + d) = w;
}

// ---- W transpose + convert: Wt[l][n][k] = bf16(Ws[l][k][n]).
// Block 0, threads 248..255 also compute per-batch valid length (mask is
// monotone) -- fused here to save one kernel launch.
__global__ __launch_bounds__(256) void wconv_kernel(const float* __restrict__ Ws,
                                                    unsigned short* __restrict__ Wt,
                                                    const void* __restrict__ maskp,
                                                    int* __restrict__ lenb) {
  if (blockIdx.x == 0 && threadIdx.x >= 248) {
    int b = threadIdx.x - 248;
    int w0 = *(const int*)maskp;
    int mode = (w0 == 1) ? 0 : ((w0 == 0x01010101) ? 1 : 2);  // i32 / u8 / f32
    int lo = 0, hi = TT;
    while (lo < hi) {
      int mid = (lo + hi) >> 1;
      int idx = b * TT + mid;
      bool mm = (mode == 0) ? (((const int*)maskp)[idx] != 0)
              : (mode == 1) ? (((const unsigned char*)maskp)[idx] != 0)
                            : (((const float*)maskp)[idx] != 0.f);
      if (mm) lo = mid + 1; else hi = mid;
    }
    lenb[b] = lo;
  }
  int idx = blockIdx.x * 256 + threadIdx.x;
  if (idx >= L_LAYERS * D * N3) return;
  int n = idx % N3;
  int k = (idx / N3) % D;
  int l = idx / (N3 * D);
  Wt[((size_t)l * N3 + n) * D + k] = f2bf(Ws[idx]);
}

// ---- 3-plane NT bf16 MFMA GEMM. One block computes a 128(m) x 128(dcol)
// output patch for ALL THREE planes (n = dcol, dcol+512, dcol+1024):
//   Ua[rec] u32 = u0 | u1<<16,  Uc[rec] u16 = u2   (rec = m*512+dcol, m=t*8+b)
// Bs columns interleaved per-16 (plane p = (c>>4)%3) so a wave's 96-col slice
// contains all 3 planes of its 32 dcols. 512 threads / 8 waves: wave covers
// 64 m x 96 c -> acc[4][6]. XCD swizzle: 4 dcol-blocks of same bm share the
// A-panel in L2.
__global__ __launch_bounds__(512) void gemm_kernel(const unsigned short* __restrict__ A,
                                                   const unsigned short* __restrict__ Bt,
                                                   unsigned* __restrict__ Ua32,
                                                   unsigned short* __restrict__ Uc16) {
  constexpr int K = D;
  __shared__ __align__(16) unsigned short As[128 * 32];   // 8 KB
  __shared__ __align__(16) unsigned short Bs[384 * 32];   // 24 KB
  int tid = threadIdx.x;
  int lane = tid & 63;
  int wave = tid >> 6;           // 0..7
  int bi = blockIdx.x;
  int xcd = bi & 7;
  int j = bi >> 3;               // 0..63
  int bm = xcd * 16 + (j >> 2);  // 0..127
  int dc0 = (j & 3) * 128;
  int m0 = bm * 128;
  int wm = (wave & 1) * 64;
  int w2 = wave >> 1;            // 0..3
  int q = lane >> 4, r16 = lane & 15;

  // staging geometry: each thread stages one 16B slot per tile
  int arow = tid >> 2;           // 0..127
  int aoff = (tid & 3) * 8;      // ushort offset within 32-col row
  int nsrc[3];
#pragma unroll
  for (int i = 0; i < 3; ++i) {
    int c = arow + i * 128;      // Bs column 0..383
    int g = c >> 4;              // 0..23
    int p = g % 3;
    int dcol = (g / 3) * 16 + (c & 15);
    nsrc[i] = dc0 + dcol + p * 512;
  }
  const unsigned short* asrc = A + (size_t)(m0 + arow) * K + aoff;

  floatx4 acc[4][6] = {};

  for (int k0 = 0; k0 < K; k0 += 32) {
    __builtin_amdgcn_global_load_lds(
        (const __attribute__((address_space(1))) unsigned int*)(asrc + k0),
        (__attribute__((address_space(3))) unsigned int*)(As + tid * 8), 16, 0, 0);
#pragma unroll
    for (int i = 0; i < 3; ++i) {
      __builtin_amdgcn_global_load_lds(
          (const __attribute__((address_space(1))) unsigned int*)(Bt + (size_t)nsrc[i] * K + k0 + aoff),
          (__attribute__((address_space(3))) unsigned int*)(Bs + i * 4096 + tid * 8), 16, 0, 0);
    }
    __syncthreads();
    short8 af[4], bfr[6];
#pragma unroll
    for (int i = 0; i < 4; ++i)
      af[i] = *(const short8*)&As[(wm + i * 16 + r16) * 32 + q * 8];
#pragma unroll
    for (int i = 0; i < 6; ++i)
      bfr[i] = *(const short8*)&Bs[(w2 * 96 + i * 16 + r16) * 32 + q * 8];
#pragma unroll
    for (int mi = 0; mi < 4; ++mi)
#pragma unroll
      for (int ni = 0; ni < 6; ++ni)
        acc[mi][ni] = __builtin_amdgcn_mfma_f32_16x16x32_bf16(af[mi], bfr[ni], acc[mi][ni], 0, 0, 0);
    __syncthreads();
  }

  // epilogue: C/D layout col=lane&15, row=(lane>>4)*4+reg (verified m89/m91)
  // frag ni: plane p = ni%3, dcol = dc0 + w2*32 + (ni/3)*16 + r16
#pragma unroll
  for (int mi = 0; mi < 4; ++mi)
#pragma unroll
    for (int half = 0; half < 2; ++half) {
      int dcol = dc0 + w2 * 32 + half * 16 + r16;
#pragma unroll
      for (int i = 0; i < 4; ++i) {
        int m = m0 + wm + mi * 16 + q * 4 + i;
        size_t rec = (size_t)m * D + dcol;
        unsigned ua = (unsigned)f2bf(acc[mi][half * 3 + 0][i]) |
                      ((unsigned)f2bf(acc[mi][half * 3 + 1][i]) << 16);
        Ua32[rec] = ua;
        Uc16[rec] = f2bf(acc[mi][half * 3 + 2][i]);
      }
    }
}

// ---- Fused chain + h: producer-consumer wave pair. 64 blocks x 128 threads.
// wave0 (tid<64): serial c-chain (minimum per-step work, R2 lesson), writes
//   each 32-step c-chunk to double-buffered LDS.
// wave1 (tid>=64): one phase behind, consumes chunk p-1 from LDS while wave0
//   computes chunk p on a different SIMD: r-gate, tanh, h blend, h/out store.
//   Its ~2000 cyc/chunk hides entirely under wave0's ~3500 cyc/chunk.
// Barrier discipline: both waves execute exactly nact barriers; buffer
// parity keeps writes (cb[p&1]) and reads (cb[(p-1)&1]) disjoint; wave1
// carries c_{t-1} across chunks in a register. Kills the c global
// round-trip (25.5 MB store + 67 MB reload per layer) and the hpost launch.
template <bool LAST>
__global__ __launch_bounds__(128) void chainh_kernel(const unsigned* __restrict__ Ua,
                                                     const unsigned short* __restrict__ Uc,
                                                     const unsigned short* __restrict__ Xin,
                                                     const float* __restrict__ vsl,
                                                     const float* __restrict__ bsl,
                                                     const int* __restrict__ lenb,
                                                     unsigned short* __restrict__ Hout,
                                                     float* __restrict__ Out) {
  __shared__ float cbuf[2][32 * 64];   // 16 KB
  int tid = threadIdx.x;
  int lane = tid & 63;
  int w = tid >> 6;                    // 0 = chain, 1 = h
  int ch = blockIdx.x * 64 + lane;
  int b = ch >> 9;                     // uniform per block
  int d = ch & 511;
  int len = lenb[b];
  int nact = (len + 31) >> 5;          // 32..64 chunks of 32 steps
  const float NL2E = -1.4426950408889634f;
  const float L2E2 = 2.8853900817779268f;
  unsigned short* ph = Hout + ch;                 // bf16 h, stride REC
  float* po = Out + (size_t)b * TT * D + d;       // f32 out, stride D

  if (w == 0) {
    // ---------------- wave0: serial chain ----------------
    float vfe = NL2E * vsl[d];
    float cbf = NL2E * bsl[d];
    const unsigned* pa = Ua + ch;
    float* cb0 = &cbuf[0][0];
    float* cb1 = &cbuf[1][0];
    unsigned uA[32], uB[32];

#define CLOAD(k, u)                                         \
  _Pragma("unroll") for (int j = 0; j < 32; ++j)            \
      u[j] = pa[(size_t)((k) * 32 + j) * REC];

#define CCOMP(k, u, cb)                                     \
  _Pragma("unroll") for (int j = 0; j < 32; ++j) {          \
    unsigned a = u[j];                                      \
    float u0 = __builtin_bit_cast(float, a << 16);          \
    float u1f = __builtin_bit_cast(float, a & 0xFFFF0000u); \
    float k1 = fmaf(u1f, NL2E, cbf);                        \
    float a2 = fmaf(vfe, c, k1);                            \
    float e = EXP2F(a2);                                    \
    float inv = RCPF(e + 1.f);                              \
    c = fmaf(c - u0, inv, u0);                              \
    cb[j * 64 + lane] = c;                                  \
  }

    CLOAD(0, uA);
    float c = 0.f;
    int p = 0;
    for (;;) {
      if (p + 1 < nact) CLOAD(p + 1, uB);
      CCOMP(p, uA, cb0);         // p even -> buffer 0
      __syncthreads();
      if (++p >= nact) break;
      if (p + 1 < nact) CLOAD(p + 1, uA);
      CCOMP(p, uB, cb1);         // p odd -> buffer 1
      __syncthreads();
      if (++p >= nact) break;
    }
#undef CLOAD
#undef CCOMP
  } else {
    // ---------------- wave1: h consumer, one phase behind ----------------
    float vre = NL2E * vsl[D + d];
    float cbr = NL2E * bsl[D + d];
    const unsigned short* pu = Uc + ch;
    const unsigned short* px = Xin + ch;
    float cprev = 0.f;

#define HPROC(q)                                                \
  {                                                             \
    int t0h = (q) * 32;                                         \
    const float* cb = &cbuf[(q) & 1][0];                        \
    unsigned short ucr[32], xxr[32];                            \
    _Pragma("unroll") for (int j = 0; j < 32; ++j) {            \
      ucr[j] = pu[(size_t)(t0h + j) * REC];                     \
      xxr[j] = px[(size_t)(t0h + j) * REC];                     \
    }                                                           \
    _Pragma("unroll") for (int j = 0; j < 32; ++j) {            \
      int t = t0h + j;                                          \
      float ct = cb[j * 64 + lane];                             \
      float u2 = __builtin_bit_cast(float, (unsigned)ucr[j] << 16); \
      float xf = __builtin_bit_cast(float, (unsigned)xxr[j] << 16); \
      float a2r = fmaf(vre, cprev, fmaf(u2, NL2E, cbr));        \
      float r = RCPF(EXP2F(a2r) + 1.f);                         \
      float et = EXP2F(ct * L2E2);                              \
      float th = fmaf(-2.f, RCPF(et + 1.f), 1.f);               \
      float hv = fmaf(r, th - xf, xf);                          \
      hv = (t < len) ? hv : 0.f;                                \
      if (LAST) po[(size_t)t * D] = hv;                         \
      else      ph[(size_t)t * REC] = f2bf(hv);                 \
      cprev = ct;                                               \
    }                                                           \
  }

    for (int p = 0; p < nact; ++p) {
      if (p > 0) HPROC(p - 1);
      __syncthreads();
    }
    HPROC(nact - 1);
#undef HPROC
  }

  // barrier-free zero tail, split across both waves (disjoint t)
  for (int t = nact * 32 + w; t < TT; t += 2) {
    if (LAST) po[(size_t)t * D] = 0.f;
    else      ph[(size_t)t * REC] = 0;
  }
}

extern "C" void kernel_launch(void* const* d_in, const int* in_sizes, int n_in,
                              void* d_out, int out_size, void* d_ws, size_t ws_size,
                              hipStream_t stream) {
  const int* ids = (const int*)d_in[0];
  const void* mask = d_in[1];
  const float* emb = (const float*)d_in[2];
  const float* Ws = (const float*)d_in[3];
  const float* vs = (const float*)d_in[4];
  const float* bs = (const float*)d_in[5];
  float* out = (float*)d_out;

  char* ws = (char*)d_ws;
  unsigned short* Ua = (unsigned short*)ws;                   // 33.5 MB dword/rec (u0|u1)
  unsigned short* Uc = Ua + (size_t)TT * REC * 2;             // 16.8 MB ushort/rec (u2)
  unsigned short* xa = Uc + (size_t)TT * REC;                 // 16.8 MB
  unsigned short* xb = xa + (size_t)TT * REC;                 // 16.8 MB
  unsigned short* Wt = xb + (size_t)TT * REC;                 // 3.1 MB
  int* lenb = (int*)(Wt + (size_t)L_LAYERS * D * N3);

  embed_kernel<<<BATCH * TT, 128, 0, stream>>>(ids, emb, xa);
  wconv_kernel<<<(L_LAYERS * D * N3 + 255) / 256, 256, 0, stream>>>(Ws, Wt, mask, lenb);

  // layer 0
  gemm_kernel<<<512, 512, 0, stream>>>(xa, Wt, (unsigned*)Ua, Uc);
  chainh_kernel<false><<<64, 128, 0, stream>>>((const unsigned*)Ua, Uc, xa,
                                               vs, bs, lenb, xb, nullptr);
  // layer 1
  gemm_kernel<<<512, 512, 0, stream>>>(xb, Wt + (size_t)N3 * D, (unsigned*)Ua, Uc);
  chainh_kernel<true><<<64, 128, 0, stream>>>((const unsigned*)Ua, Uc, xb,
                                              vs + 2 * D, bs + 2 * D, lenb, nullptr, out);
}

// Round 6
// 457.497 us; speedup vs baseline: 1.4706x; 1.4706x over previous
//
#include <hip/hip_runtime.h>
#include <hip/hip_bf16.h>

#define D 512
#define L_LAYERS 2
#define BATCH 8
#define TT 2048
#define N3 1536   // 3*D
#define REC 4096  // BATCH*D

typedef __attribute__((ext_vector_type(8))) short short8;
typedef __attribute__((ext_vector_type(4))) float floatx4;

#if __has_builtin(__builtin_amdgcn_exp2f)
#define EXP2F(x) __builtin_amdgcn_exp2f(x)
#else
#define EXP2F(x) exp2f(x)
#endif
#if __has_builtin(__builtin_amdgcn_rcpf)
#define RCPF(x) __builtin_amdgcn_rcpf(x)
#else
#define RCPF(x) (1.0f / (x))
#endif

__device__ __forceinline__ unsigned short f2bf(float f) {
  unsigned u = __builtin_bit_cast(unsigned, f);
  u += 0x7FFFu + ((u >> 16) & 1u);
  return (unsigned short)(u >> 16);
}

// ---- embedding gather: xa[(t*B+b)*D + d] = bf16(emb[ids[b][t]][d])
__global__ __launch_bounds__(128) void embed_kernel(const int* __restrict__ ids,
                                                    const float* __restrict__ emb,
                                                    unsigned short* __restrict__ xa) {
  int bt = blockIdx.x;          // b*T + t
  int b = bt >> 11;
  int t = bt & 2047;
  int id = ids[bt];
  int d = threadIdx.x << 2;
  const float4 v = *(const float4*)(emb + (size_t)id * D + d);
  ushort4 w;
  w.x = f2bf(v.x); w.y = f2bf(v.y); w.z = f2bf(v.z); w.w = f2bf(v.w);
  *(ushort4*)(xa + ((size_t)t * BATCH + b) * D + d) = w;
}

// ---- W transpose + convert: Wt[l][n][k] = bf16(Ws[l][k][n]).
// Block 0, threads 248..255 also compute per-batch valid length (mask is
// monotone) -- fused here to save one kernel launch.
__global__ __launch_bounds__(256) void wconv_kernel(const float* __restrict__ Ws,
                                                    unsigned short* __restrict__ Wt,
                                                    const void* __restrict__ maskp,
                                                    int* __restrict__ lenb) {
  if (blockIdx.x == 0 && threadIdx.x >= 248) {
    int b = threadIdx.x - 248;
    int w0 = *(const int*)maskp;
    int mode = (w0 == 1) ? 0 : ((w0 == 0x01010101) ? 1 : 2);  // i32 / u8 / f32
    int lo = 0, hi = TT;
    while (lo < hi) {
      int mid = (lo + hi) >> 1;
      int idx = b * TT + mid;
      bool mm = (mode == 0) ? (((const int*)maskp)[idx] != 0)
              : (mode == 1) ? (((const unsigned char*)maskp)[idx] != 0)
                            : (((const float*)maskp)[idx] != 0.f);
      if (mm) lo = mid + 1; else hi = mid;
    }
    lenb[b] = lo;
  }
  int idx = blockIdx.x * 256 + threadIdx.x;
  if (idx >= L_LAYERS * D * N3) return;
  int n = idx % N3;
  int k = (idx / N3) % D;
  int l = idx / (N3 * D);
  Wt[((size_t)l * N3 + n) * D + k] = f2bf(Ws[idx]);
}

// ---- 3-plane NT bf16 MFMA GEMM, 2-phase double-buffered K-loop (T3-min).
// One block computes a 128(m) x 128(dcol) output patch for ALL THREE planes
// (n = dcol, dcol+512, dcol+1024):
//   Ua[rec] u32 = u0 | u1<<16,  Uc[rec] u16 = u2   (rec = m*512+dcol, m=t*8+b)
// K-loop: issue STAGE(next) BEFORE computing current buffer; ONE barrier per
// iteration (vs the old stage->sync->compute->sync) so the ~600cyc global->LDS
// latency hides under 24 MFMAs. LDS 64KB -> 2 blocks/CU (fits 160KB).
// Bs columns interleaved per-16 (plane p = (c>>4)%3) so a wave's 96-col slice
// contains all 3 planes of its 32 dcols. 512 threads / 8 waves: wave covers
// 64 m x 96 c -> acc[4][6]. XCD swizzle: 4 dcol-blocks of same bm share the
// A-panel in L2.
__global__ __launch_bounds__(512) void gemm_kernel(const unsigned short* __restrict__ A,
                                                   const unsigned short* __restrict__ Bt,
                                                   unsigned* __restrict__ Ua32,
                                                   unsigned short* __restrict__ Uc16) {
  constexpr int K = D;
  __shared__ __align__(16) unsigned short As[2][128 * 32];   // 16 KB
  __shared__ __align__(16) unsigned short Bs[2][384 * 32];   // 48 KB
  int tid = threadIdx.x;
  int lane = tid & 63;
  int wave = tid >> 6;           // 0..7
  int bi = blockIdx.x;
  int xcd = bi & 7;
  int j = bi >> 3;               // 0..63
  int bm = xcd * 16 + (j >> 2);  // 0..127
  int dc0 = (j & 3) * 128;
  int m0 = bm * 128;
  int wm = (wave & 1) * 64;
  int w2 = wave >> 1;            // 0..3
  int q = lane >> 4, r16 = lane & 15;

  // staging geometry: each thread stages one 16B slot per plane per tile
  int arow = tid >> 2;           // 0..127
  int aoff = (tid & 3) * 8;      // ushort offset within 32-col row
  int nsrc[3];
#pragma unroll
  for (int i = 0; i < 3; ++i) {
    int c = arow + i * 128;      // Bs column 0..383
    int g = c >> 4;              // 0..23
    int p = g % 3;
    int dcol = (g / 3) * 16 + (c & 15);
    nsrc[i] = dc0 + dcol + p * 512;
  }
  const unsigned short* asrc = A + (size_t)(m0 + arow) * K + aoff;

  floatx4 acc[4][6] = {};

#define GSTAGE(bufi, k0s)                                                                  \
  {                                                                                        \
    __builtin_amdgcn_global_load_lds(                                                      \
        (const __attribute__((address_space(1))) unsigned int*)(asrc + (k0s)),             \
        (__attribute__((address_space(3))) unsigned int*)(&As[bufi][tid * 8]), 16, 0, 0);  \
    _Pragma("unroll")                                                                      \
    for (int i = 0; i < 3; ++i) {                                                          \
      __builtin_amdgcn_global_load_lds(                                                    \
          (const __attribute__((address_space(1))) unsigned int*)(Bt + (size_t)nsrc[i] * K + (k0s) + aoff), \
          (__attribute__((address_space(3))) unsigned int*)(&Bs[bufi][i * 4096 + tid * 8]), 16, 0, 0);      \
    }                                                                                      \
  }

  GSTAGE(0, 0);
  __syncthreads();               // buf0 ready
  int cur = 0;
  for (int k0 = 0; k0 < K; k0 += 32) {
    if (k0 + 32 < K) GSTAGE(cur ^ 1, k0 + 32);   // prefetch next tile (in flight across MFMA)
    short8 af[4], bfr[6];
#pragma unroll
    for (int i = 0; i < 4; ++i)
      af[i] = *(const short8*)&As[cur][(wm + i * 16 + r16) * 32 + q * 8];
#pragma unroll
    for (int i = 0; i < 6; ++i)
      bfr[i] = *(const short8*)&Bs[cur][(w2 * 96 + i * 16 + r16) * 32 + q * 8];
#pragma unroll
    for (int mi = 0; mi < 4; ++mi)
#pragma unroll
      for (int ni = 0; ni < 6; ++ni)
        acc[mi][ni] = __builtin_amdgcn_mfma_f32_16x16x32_bf16(af[mi], bfr[ni], acc[mi][ni], 0, 0, 0);
    __syncthreads();             // = vmcnt(0)+lgkmcnt(0)+barrier: next buf ready, reads of cur done
    cur ^= 1;
  }
#undef GSTAGE

  // epilogue: C/D layout col=lane&15, row=(lane>>4)*4+reg (verified m89/m91)
  // frag ni: plane p = ni%3, dcol = dc0 + w2*32 + (ni/3)*16 + r16
#pragma unroll
  for (int mi = 0; mi < 4; ++mi)
#pragma unroll
    for (int half = 0; half < 2; ++half) {
      int dcol = dc0 + w2 * 32 + half * 16 + r16;
#pragma unroll
      for (int i = 0; i < 4; ++i) {
        int m = m0 + wm + mi * 16 + q * 4 + i;
        size_t rec = (size_t)m * D + dcol;
        unsigned ua = (unsigned)f2bf(acc[mi][half * 3 + 0][i]) |
                      ((unsigned)f2bf(acc[mi][half * 3 + 1][i]) << 16);
        Ua32[rec] = ua;
        Uc16[rec] = f2bf(acc[mi][half * 3 + 2][i]);
      }
    }
}

// ---- Kernel A: serial c-chain, register-double-buffered global loads.
// 64 blocks x 64 threads (1 wave/block). Minimum per-step work only; R2+R5
// both proved adding ANY h-work (same-wave or sibling-wave+barriers) to the
// serial phase regresses 2-3x. ~93.2 us ~= dep-chain floor (fma->exp->add->
// rcp->fma ~100 cyc/step incl. wave64 trans latency).
__global__ __launch_bounds__(64) void cchain_kernel(unsigned* __restrict__ Uac,
                                                    const float* __restrict__ vsl,
                                                    const float* __restrict__ bsl,
                                                    const int* __restrict__ lenb) {
  int tid = threadIdx.x;
  int ch = blockIdx.x * 64 + tid;
  int b = ch >> 9;              // uniform per block
  int d = ch & 511;
  int len = lenb[b];
  const float NL2E = -1.4426950408889634f;
  float vfe = NL2E * vsl[d];
  float cbf = NL2E * bsl[d];
  const unsigned* pa = Uac + ch;
  float* pc = (float*)Uac + ch;
  int nact = (len + 31) >> 5;   // 32..64 chunks of 32 steps

  unsigned uA[32], uB[32];

#define CLOAD(k, u)                                         \
  _Pragma("unroll") for (int j = 0; j < 32; ++j)            \
      u[j] = pa[(size_t)((k) * 32 + j) * REC];

#define CCOMP(k, u)                                         \
  _Pragma("unroll") for (int j = 0; j < 32; ++j) {          \
    unsigned a = u[j];                                      \
    float u0 = __builtin_bit_cast(float, a << 16);          \
    float u1f = __builtin_bit_cast(float, a & 0xFFFF0000u); \
    float k1 = fmaf(u1f, NL2E, cbf);                        \
    float a2 = fmaf(vfe, c, k1);                            \
    float e = EXP2F(a2);                                    \
    float inv = RCPF(e + 1.f);                              \
    c = fmaf(c - u0, inv, u0);                              \
    pc[(size_t)((k) * 32 + j) * REC] = c;                   \
  }

  CLOAD(0, uA);
  float c = 0.f;
  int k = 0;
  for (;;) {
    if (k + 1 < nact) CLOAD(k + 1, uB);
    CCOMP(k, uA);
    if (++k >= nact) break;
    if (k + 1 < nact) CLOAD(k + 1, uA);
    CCOMP(k, uB);
    if (++k >= nact) break;
  }
#undef CLOAD
#undef CCOMP
  // t >= nact*32: c region stale; hpost masks h=0 there, never reads stale c into output.
}

// ---- Kernel B: parallel h epilogue. h_t = r*tanh(c_t) + (1-r)*x, r = sigm(u2+vr*c_{t-1}+br).
// u2 from Uc (ushort plane), x from the layer input xa/xb (same rec layout).
template <bool LAST>
__global__ __launch_bounds__(256) void hpost_kernel(const unsigned short* __restrict__ Uc,
                                                    const unsigned short* __restrict__ Xin,
                                                    const float4* __restrict__ cq,
                                                    const float* __restrict__ vsl,
                                                    const float* __restrict__ bsl,
                                                    const int* __restrict__ lenb,
                                                    unsigned short* __restrict__ Hout,
                                                    float* __restrict__ Out) {
  int idx = blockIdx.x * 256 + threadIdx.x;   // = t*1024 + q
  int t = idx >> 10;
  int q = idx & 1023;
  int rec0 = q << 2;
  int b = rec0 >> 9;
  int d = rec0 & 511;
  int len = lenb[b];
  ushort4 uv = *(const ushort4*)(Uc + (size_t)idx * 4);
  ushort4 xv = *(const ushort4*)(Xin + (size_t)idx * 4);
  float4 ct = cq[idx];
  float4 cp = (t > 0) ? cq[idx - 1024] : make_float4(0.f, 0.f, 0.f, 0.f);
  float4 vr4 = *(const float4*)(vsl + D + d);
  float4 br4 = *(const float4*)(bsl + D + d);
  const float NL2E = -1.4426950408889634f;
  const float L2E2 = 2.8853900817779268f;
  unsigned uu[4] = {uv.x, uv.y, uv.z, uv.w};
  unsigned xx[4] = {xv.x, xv.y, xv.z, xv.w};
  float cta[4] = {ct.x, ct.y, ct.z, ct.w};
  float cpa[4] = {cp.x, cp.y, cp.z, cp.w};
  float vra[4] = {vr4.x, vr4.y, vr4.z, vr4.w};
  float bra[4] = {br4.x, br4.y, br4.z, br4.w};
  bool act = t < len;
  float h[4];
#pragma unroll
  for (int j = 0; j < 4; ++j) {
    float u2 = __builtin_bit_cast(float, uu[j] << 16);
    float xf = __builtin_bit_cast(float, xx[j] << 16);
    float k2 = fmaf(u2, NL2E, NL2E * bra[j]);
    float a2 = fmaf(NL2E * vra[j], cpa[j], k2);
    float r = RCPF(EXP2F(a2) + 1.f);
    float et = EXP2F(cta[j] * L2E2);
    float th = fmaf(-2.f, RCPF(et + 1.f), 1.f);
    float hv = fmaf(r, th - xf, xf);
    h[j] = act ? hv : 0.f;
  }
  if (LAST) {
    *(float4*)(Out + ((size_t)b * TT + t) * D + d) = make_float4(h[0], h[1], h[2], h[3]);
  } else {
    ushort4 o; o.x = f2bf(h[0]); o.y = f2bf(h[1]); o.z = f2bf(h[2]); o.w = f2bf(h[3]);
    *(ushort4*)(Hout + (size_t)idx * 4) = o;    // (t*8+b)*512+d == idx*4
  }
}

extern "C" void kernel_launch(void* const* d_in, const int* in_sizes, int n_in,
                              void* d_out, int out_size, void* d_ws, size_t ws_size,
                              hipStream_t stream) {
  const int* ids = (const int*)d_in[0];
  const void* mask = d_in[1];
  const float* emb = (const float*)d_in[2];
  const float* Ws = (const float*)d_in[3];
  const float* vs = (const float*)d_in[4];
  const float* bs = (const float*)d_in[5];
  float* out = (float*)d_out;

  char* ws = (char*)d_ws;
  unsigned short* Ua = (unsigned short*)ws;                   // 33.5 MB dword/rec (u0|u1; later c as f32)
  unsigned short* Uc = Ua + (size_t)TT * REC * 2;             // 16.8 MB ushort/rec (u2)
  unsigned short* xa = Uc + (size_t)TT * REC;                 // 16.8 MB
  unsigned short* xb = xa + (size_t)TT * REC;                 // 16.8 MB
  unsigned short* Wt = xb + (size_t)TT * REC;                 // 3.1 MB
  int* lenb = (int*)(Wt + (size_t)L_LAYERS * D * N3);

  embed_kernel<<<BATCH * TT, 128, 0, stream>>>(ids, emb, xa);
  wconv_kernel<<<(L_LAYERS * D * N3 + 255) / 256, 256, 0, stream>>>(Ws, Wt, mask, lenb);

  // layer 0
  gemm_kernel<<<512, 512, 0, stream>>>(xa, Wt, (unsigned*)Ua, Uc);
  cchain_kernel<<<64, 64, 0, stream>>>((unsigned*)Ua, vs, bs, lenb);
  hpost_kernel<false><<<8192, 256, 0, stream>>>(Uc, xa, (const float4*)Ua,
                                                vs, bs, lenb, xb, nullptr);
  // layer 1
  gemm_kernel<<<512, 512, 0, stream>>>(xb, Wt + (size_t)N3 * D, (unsigned*)Ua, Uc);
  cchain_kernel<<<64, 64, 0, stream>>>((unsigned*)Ua, vs + 2 * D, bs + 2 * D, lenb);
  hpost_kernel<true><<<8192, 256, 0, stream>>>(Uc, xb, (const float4*)Ua,
                                               vs + 2 * D, bs + 2 * D, lenb, nullptr, out);
}